// Round 16
// baseline (124.388 us; speedup 1.0000x reference)
//
#include <hip/hip_runtime.h>

#define D        128
#define CH       16     // chunks per cell line; grid = 64*CH = 1024 blocks
#define TPB      512    // 8 waves = 2 sub-blocks of 256 (sub = tid>>8)
#define EPP      4      // elements per pass PER SUB-BLOCK (8 per block-pass)
#define LIST_CAP 128    // n ~ Binomial(512,1/64), mean 8; 128 is safe

// W_c and P_c live in REGISTERS (16+16 float4 per thread), loaded once per
// block. Two 256-thread sub-blocks process 4 elements each per pass ->
// >=2 waves/SIMD resident even at 1 block/CU (round-13 showed the wall is
// the per-pass latency chain at ~1 wave/SIMD; TPB=512 doubles hiding).
// x-gathers are prefetched to registers BEFORE W/P staging so their latency
// overlaps the 64 staging loads.
__global__ __launch_bounds__(TPB, 2) void ipp_main(
    const int* __restrict__ dp, const int* __restrict__ cl,
    const float* __restrict__ hd, const float* __restrict__ W_all,
    const float* __restrict__ P_all, float* __restrict__ out,
    int B, int range)
{
    __shared__ float  sx[2][8][D];        // [sub] pass rows (x, then t)
    __shared__ float  sh[2][8][D];        // [sub] h rows
    __shared__ float4 part[2][4][8][32];  // [sub][wave][row][c4] partials
    __shared__ int    list[LIST_CAP];
    __shared__ int    lcount;

    const int tid  = threadIdx.x;
    const int c    = blockIdx.x / CH;
    const int chunk= blockIdx.x % CH;
    const int sub  = tid >> 8;           // sub-block 0/1
    const int stid = tid & 255;
    const int g    = stid >> 5;          // d-slab [g*16, g*16+16)
    const int c4   = stid & 31;          // float4 column chunk
    const int wv   = stid >> 6;          // wave-in-sub 0..3

    if (tid == 0) lcount = 0;
    __syncthreads();

    // build match list for this (c, chunk); range=512 -> exactly 1 iter
    {
        const int base = chunk * range;
        const int end  = min(base + range, B);
        for (int j = base + tid; j < end; j += TPB)
            if (cl[j] == c) {
                int p = atomicAdd(&lcount, 1);
                if (p < LIST_CAP) list[p] = j;
            }
    }
    __syncthreads();
    const int n     = min(lcount, LIST_CAP);
    const int npass = (n + 2 * EPP - 1) / (2 * EPP);

    // ---- pass-0 x prefetch: issue gather BEFORE W/P staging ----
    // thread's row: elem e=g>>1 (of its sub-block), operand op=g&1
    float4 xv = make_float4(0.f, 0.f, 0.f, 0.f);
    if (n > 0) {
        const int pe = 0 * 2 * EPP + sub * EPP + (g >> 1);
        const int b  = list[pe < n ? pe : 0];
        const int dr = dp[2 * b + (g & 1)];
        xv = ((const float4*)(hd + (size_t)dr * D))[c4];
    }

    // load W/P tiles into registers (coalesced; overlaps the xv gather)
    float4 Wreg[16], Preg[16];
    {
        const float4* gW = (const float4*)(W_all + (size_t)c * D * D);
        const float4* gP = (const float4*)(P_all + (size_t)c * D * D);
        #pragma unroll
        for (int dd = 0; dd < 16; ++dd) {
            Wreg[dd] = gW[(g * 16 + dd) * 32 + c4];
            Preg[dd] = gP[(g * 16 + dd) * 32 + c4];
        }
    }

// NOTE: macro parameter names must not collide with float4 members!
#define FMA4(A_, S_, W_)                                                       \
    (A_).x = fmaf((S_), (W_).x, (A_).x);                                       \
    (A_).y = fmaf((S_), (W_).y, (A_).y);                                       \
    (A_).z = fmaf((S_), (W_).z, (A_).z);                                       \
    (A_).w = fmaf((S_), (W_).w, (A_).w);

// acc[e][op] += (rows from SRC) x (register tile REG); partials -> OUT
#define MATTILE(SRC, REG, OUT)                                                 \
    {                                                                          \
        _Pragma("unroll")                                                      \
        for (int q = 0; q < 4; ++q) {                                          \
            _Pragma("unroll")                                                  \
            for (int r = 0; r < 8; ++r) {                                      \
                const float4 xq = ((const float4*)(SRC)[r])[g * 4 + q];        \
                float4& ac = acc[r >> 1][r & 1];                               \
                FMA4(ac, xq.x, REG[q * 4 + 0])                                 \
                FMA4(ac, xq.y, REG[q * 4 + 1])                                 \
                FMA4(ac, xq.z, REG[q * 4 + 2])                                 \
                FMA4(ac, xq.w, REG[q * 4 + 3])                                 \
            }                                                                  \
        }                                                                      \
        _Pragma("unroll")                                                      \
        for (int e = 0; e < EPP; ++e) {                                        \
            _Pragma("unroll")                                                  \
            for (int op = 0; op < 2; ++op) {                                   \
                float4& ac = acc[e][op];                                       \
                ac.x += __shfl_xor(ac.x, 32, 64);                              \
                ac.y += __shfl_xor(ac.y, 32, 64);                              \
                ac.z += __shfl_xor(ac.z, 32, 64);                              \
                ac.w += __shfl_xor(ac.w, 32, 64);                              \
            }                                                                  \
        }                                                                      \
        if ((stid & 32) == 0) {                                                \
            _Pragma("unroll")                                                  \
            for (int r = 0; r < 8; ++r)                                        \
                (OUT)[wv][r][c4] = acc[r >> 1][r & 1];                         \
        }                                                                      \
    }

    for (int pass = 0; pass < npass; ++pass) {
        const int pbase = pass * 2 * EPP + sub * EPP;

        if (pass > 0) {   // inline gather for later passes (rare)
            const int pe = pbase + (g >> 1);
            const int b  = list[pe < n ? pe : 0];
            const int dr = dp[2 * b + (g & 1)];
            xv = ((const float4*)(hd + (size_t)dr * D))[c4];
        }
        ((float4*)sx[sub][g])[c4] = xv;
        __syncthreads();

        // ---- phase 1: rows @ W -> relu -> sh ----
        float4 acc[EPP][2];
        #pragma unroll
        for (int e = 0; e < EPP; ++e)
            #pragma unroll
            for (int op = 0; op < 2; ++op)
                acc[e][op] = make_float4(0.f, 0.f, 0.f, 0.f);
        MATTILE(sx[sub], Wreg, part[sub])
        __syncthreads();
        {
            const float4 s0 = part[sub][0][g][c4], s1 = part[sub][1][g][c4];
            const float4 s2 = part[sub][2][g][c4], s3 = part[sub][3][g][c4];
            float4 s;
            s.x = fmaxf(s0.x + s1.x + s2.x + s3.x, 0.f);
            s.y = fmaxf(s0.y + s1.y + s2.y + s3.y, 0.f);
            s.z = fmaxf(s0.z + s1.z + s2.z + s3.z, 0.f);
            s.w = fmaxf(s0.w + s1.w + s2.w + s3.w, 0.f);
            ((float4*)sh[sub][g])[c4] = s;
        }
        __syncthreads();

        // ---- phase 2: h-rows @ P -> t (reuse sx) ----
        #pragma unroll
        for (int e = 0; e < EPP; ++e)
            #pragma unroll
            for (int op = 0; op < 2; ++op)
                acc[e][op] = make_float4(0.f, 0.f, 0.f, 0.f);
        MATTILE(sh[sub], Preg, part[sub])
        __syncthreads();
        {
            const float4 s0 = part[sub][0][g][c4], s1 = part[sub][1][g][c4];
            const float4 s2 = part[sub][2][g][c4], s3 = part[sub][3][g][c4];
            float4 s;
            s.x = s0.x + s1.x + s2.x + s3.x;
            s.y = s0.y + s1.y + s2.y + s3.y;
            s.z = s0.z + s1.z + s2.z + s3.z;
            s.w = s0.w + s1.w + s2.w + s3.w;
            ((float4*)sx[sub][g])[c4] = s;
        }
        __syncthreads();

        // ---- out[e] = t1.h2 + t2.h1 ; one wave per element ----
        {
            const int e  = stid >> 6;
            const int k2 = (stid & 63) * 2;
            const float* t1 = sx[sub][2 * e], * t2 = sx[sub][2 * e + 1];
            const float* h1 = sh[sub][2 * e], * h2 = sh[sub][2 * e + 1];
            float prt = t1[k2] * h2[k2] + t1[k2 + 1] * h2[k2 + 1]
                      + t2[k2] * h1[k2] + t2[k2 + 1] * h1[k2 + 1];
            #pragma unroll
            for (int off = 32; off; off >>= 1)
                prt += __shfl_down(prt, off, 64);
            const int pe = pbase + e;
            if ((stid & 63) == 0 && pe < n) out[list[pe]] = prt;
        }
        __syncthreads();   // protect sx/sh before next pass staging
    }
#undef MATTILE
#undef FMA4
}

extern "C" void kernel_launch(void* const* d_in, const int* in_sizes, int n_in,
                              void* d_out, int out_size, void* d_ws, size_t ws_size,
                              hipStream_t stream) {
    const int*   dp    = (const int*)  d_in[0];
    const int*   cl    = (const int*)  d_in[1];
    const float* hd    = (const float*)d_in[2];
    const float* W_all = (const float*)d_in[3];
    const float* P_all = (const float*)d_in[4];
    float*       out   = (float*)d_out;

    const int B     = out_size;                 // 8192
    const int ncl   = in_sizes[4] / (D * D);    // 64
    const int range = (B + CH - 1) / CH;        // 512

    ipp_main<<<dim3(ncl * CH), dim3(TPB), 0, stream>>>(
        dp, cl, hd, W_all, P_all, out, B, range);
}

// Round 17
// 111.730 us; speedup vs baseline: 1.1133x; 1.1133x over previous
//
#include <hip/hip_runtime.h>

#define D        128
#define NCL      64     // cell lines
#define CH       32     // chunks per cell line; grid = 64*CH = 2048 blocks
#define TPB      256    // 4 waves: 32 col-quads (c4) x 8 d-slabs (g) of 16
#define EPP      4      // elements per pass (8 rows with the 2-operand trick)
#define LIST_CAP 128    // n ~ Binomial(256,1/64), mean 4

// Round-13 structure + ONE change: chunk-major block remap so all CH blocks
// of a cell line land on the SAME XCD (blockIdx%8 == c%8 for every chunk).
// Theory: dur == FETCH/BW in all 5 measured configs (fetch-latency-bound);
// default mapping scatters same-c blocks across XCDs -> W/P (8MB) thrashes
// every 4MB per-XCD L2 -> ~600cyc L3 trips at ~600-730 GB/s. Chunk-major
// gives each XCD an 8-cell-line hot set (1MB W/P + 2MB h_drug < 4MB L2).
__global__ __launch_bounds__(TPB, 2) void ipp_main(
    const int* __restrict__ dp, const int* __restrict__ cl,
    const float* __restrict__ hd, const float* __restrict__ W_all,
    const float* __restrict__ P_all, float* __restrict__ out,
    int B, int range)
{
    __shared__ float  sx[8][D];          // pass rows (x, then reused for t)
    __shared__ float  sh[8][D];          // h rows
    __shared__ float4 part[4][8][32];    // [wave][row][c4] partials, 16 KB
    __shared__ int    list[LIST_CAP];
    __shared__ int    lcount;

    const int tid   = threadIdx.x;
    const int c     = blockIdx.x % NCL;  // chunk-major: same-c -> same XCD
    const int chunk = blockIdx.x / NCL;
    const int g     = tid >> 5;          // d-slab [g*16, g*16+16)
    const int c4    = tid & 31;          // float4 column chunk
    const int wv    = tid >> 6;          // wave 0..3

    if (tid == 0) lcount = 0;
    __syncthreads();

    // build match list for this (c, chunk)
    {
        const int base = chunk * range;
        const int end  = min(base + range, B);
        for (int j = base + tid; j < end; j += TPB)
            if (cl[j] == c) {
                int p = atomicAdd(&lcount, 1);
                if (p < LIST_CAP) list[p] = j;
            }
    }

    // load W/P tiles into registers (coalesced global reads, once per block)
    float4 Wreg[16], Preg[16];
    {
        const float4* gW = (const float4*)(W_all + (size_t)c * D * D);
        const float4* gP = (const float4*)(P_all + (size_t)c * D * D);
        #pragma unroll
        for (int dd = 0; dd < 16; ++dd) {
            Wreg[dd] = gW[(g * 16 + dd) * 32 + c4];
            Preg[dd] = gP[(g * 16 + dd) * 32 + c4];
        }
    }
    __syncthreads();
    const int n = min(lcount, LIST_CAP);

// NOTE: parameter names must not collide with float4 members (.x/.y/.z/.w)!
#define FMA4(A_, S_, W_)                                                       \
    (A_).x = fmaf((S_), (W_).x, (A_).x);                                       \
    (A_).y = fmaf((S_), (W_).y, (A_).y);                                       \
    (A_).z = fmaf((S_), (W_).z, (A_).z);                                       \
    (A_).w = fmaf((S_), (W_).w, (A_).w);

// acc[e][op] += (rows from SRC) x (register tile REG) over this thread's slab
#define MATTILE(SRC, REG)                                                      \
    {                                                                          \
        _Pragma("unroll")                                                      \
        for (int q = 0; q < 4; ++q) {                                          \
            _Pragma("unroll")                                                  \
            for (int r = 0; r < 8; ++r) {                                      \
                const float4 xq = ((const float4*)(SRC)[r])[g * 4 + q];        \
                float4& ac = acc[r >> 1][r & 1];                               \
                FMA4(ac, xq.x, REG[q * 4 + 0])                                 \
                FMA4(ac, xq.y, REG[q * 4 + 1])                                 \
                FMA4(ac, xq.z, REG[q * 4 + 2])                                 \
                FMA4(ac, xq.w, REG[q * 4 + 3])                                 \
            }                                                                  \
        }                                                                      \
        _Pragma("unroll")                                                      \
        for (int e = 0; e < EPP; ++e) {                                        \
            _Pragma("unroll")                                                  \
            for (int op = 0; op < 2; ++op) {                                   \
                float4& ac = acc[e][op];                                       \
                ac.x += __shfl_xor(ac.x, 32, 64);                              \
                ac.y += __shfl_xor(ac.y, 32, 64);                              \
                ac.z += __shfl_xor(ac.z, 32, 64);                              \
                ac.w += __shfl_xor(ac.w, 32, 64);                              \
            }                                                                  \
        }                                                                      \
        if ((tid & 32) == 0) {                                                 \
            _Pragma("unroll")                                                  \
            for (int r = 0; r < 8; ++r)                                        \
                part[wv][r][c4] = acc[r >> 1][r & 1];                          \
        }                                                                      \
    }

    const int npass = (n + EPP - 1) / EPP;
    for (int pass = 0; pass < npass; ++pass) {
        const int pbase = pass * EPP;

        // stage x rows: row g = elem(g>>1), drug-op(g&1); one float4 per thread
        {
            const int e  = g >> 1, op = g & 1;
            const int pe = pbase + e;
            const int b  = list[pe < n ? pe : 0];
            const int dr = dp[2 * b + op];
            ((float4*)sx[g])[c4] = ((const float4*)(hd + (size_t)dr * D))[c4];
        }
        __syncthreads();

        // ---- phase 1: rows @ W ----
        float4 acc[EPP][2];
        #pragma unroll
        for (int e = 0; e < EPP; ++e)
            #pragma unroll
            for (int op = 0; op < 2; ++op)
                acc[e][op] = make_float4(0.f, 0.f, 0.f, 0.f);
        MATTILE(sx, Wreg)
        __syncthreads();
        {   // reduce 4 wave-partials per column, relu -> sh (row g, quad c4)
            const float4 s0 = part[0][g][c4], s1 = part[1][g][c4];
            const float4 s2 = part[2][g][c4], s3 = part[3][g][c4];
            float4 s;
            s.x = fmaxf(s0.x + s1.x + s2.x + s3.x, 0.f);
            s.y = fmaxf(s0.y + s1.y + s2.y + s3.y, 0.f);
            s.z = fmaxf(s0.z + s1.z + s2.z + s3.z, 0.f);
            s.w = fmaxf(s0.w + s1.w + s2.w + s3.w, 0.f);
            ((float4*)sh[g])[c4] = s;
        }
        __syncthreads();

        // ---- phase 2: h-rows @ P ----
        #pragma unroll
        for (int e = 0; e < EPP; ++e)
            #pragma unroll
            for (int op = 0; op < 2; ++op)
                acc[e][op] = make_float4(0.f, 0.f, 0.f, 0.f);
        MATTILE(sh, Preg)
        __syncthreads();
        {   // reduce (no relu) -> t rows (reuse sx)
            const float4 s0 = part[0][g][c4], s1 = part[1][g][c4];
            const float4 s2 = part[2][g][c4], s3 = part[3][g][c4];
            float4 s;
            s.x = s0.x + s1.x + s2.x + s3.x;
            s.y = s0.y + s1.y + s2.y + s3.y;
            s.z = s0.z + s1.z + s2.z + s3.z;
            s.w = s0.w + s1.w + s2.w + s3.w;
            ((float4*)sx[g])[c4] = s;
        }
        __syncthreads();

        // ---- out[e] = t1.h2 + t2.h1 ; one wave per element ----
        {
            const int e  = tid >> 6;
            const int k2 = (tid & 63) * 2;
            const float* t1 = sx[2 * e],     * t2 = sx[2 * e + 1];
            const float* h1 = sh[2 * e],     * h2 = sh[2 * e + 1];
            float prt = t1[k2] * h2[k2] + t1[k2 + 1] * h2[k2 + 1]
                      + t2[k2] * h1[k2] + t2[k2 + 1] * h1[k2 + 1];
            #pragma unroll
            for (int off = 32; off; off >>= 1)
                prt += __shfl_down(prt, off, 64);
            const int pe = pbase + e;
            if ((tid & 63) == 0 && pe < n) out[list[pe]] = prt;
        }
        __syncthreads();   // protect sx/sh before next pass staging
    }
#undef MATTILE
#undef FMA4
}

extern "C" void kernel_launch(void* const* d_in, const int* in_sizes, int n_in,
                              void* d_out, int out_size, void* d_ws, size_t ws_size,
                              hipStream_t stream) {
    const int*   dp    = (const int*)  d_in[0];
    const int*   cl    = (const int*)  d_in[1];
    const float* hd    = (const float*)d_in[2];
    const float* W_all = (const float*)d_in[3];
    const float* P_all = (const float*)d_in[4];
    float*       out   = (float*)d_out;

    const int B     = out_size;                 // 8192
    const int range = (B + CH - 1) / CH;        // 256

    ipp_main<<<dim3(NCL * CH), dim3(TPB), 0, stream>>>(
        dp, cl, hd, W_all, P_all, out, B, range);
}